// Round 13
// baseline (655.769 us; speedup 1.0000x reference)
//
#include <hip/hip_runtime.h>
#include <hip/hip_cooperative_groups.h>

namespace cg = cooperative_groups;

#define C_IN 256
#define C_OUT 256
#define NH 4
#define HD 64
#define NEG_SLOPE 0.2f

typedef _Float16 half8 __attribute__((ext_vector_type(8)));
typedef _Float16 half4v __attribute__((ext_vector_type(4)));
typedef float floatx4 __attribute__((ext_vector_type(4)));

// ---------------------------------------------------------------------------
// PREP (merged): blocks [0,256] = make_eff_w; [257,512] = transpose_w;
// [513,...] = deg + RANK (atomicAdd return = within-segment rank).
// ---------------------------------------------------------------------------
__global__ void prep_kernel(const float* __restrict__ Wl, const float* __restrict__ Wr,
                            const float* __restrict__ bl, const float* __restrict__ br,
                            const float* __restrict__ attl, const float* __restrict__ attr,
                            const float* __restrict__ Wv, const int* __restrict__ dst,
                            float* __restrict__ Ws, float* __restrict__ bs,
                            _Float16* __restrict__ WvT, int* __restrict__ deg,
                            int* __restrict__ rank, int E)
{
    int bid = blockIdx.x;
    int t = threadIdx.x;
    if (bid <= C_IN) {
        int c = bid;
        int h = t >> 6, d = t & 63;
        float al = attl[t], ar = attr[t];
        float vl, vr;
        if (c < C_IN) { vl = Wl[c * C_OUT + t] * al; vr = Wr[c * C_OUT + t] * ar; }
        else          { vl = bl[t] * al;             vr = br[t] * ar; }
#pragma unroll
        for (int off = 32; off >= 1; off >>= 1) {
            vl += __shfl_xor(vl, off, 64);
            vr += __shfl_xor(vr, off, 64);
        }
        if (d == 0) {
            if (c < C_IN) { Ws[c * 8 + h] = vl; Ws[c * 8 + 4 + h] = vr; }
            else          { bs[h] = vl;         bs[4 + h] = vr; }
        }
    } else if (bid <= C_IN + 256) {
        int idx = (bid - (C_IN + 1)) * 256 + t;
        int n = idx >> 8, k = idx & 255;
        WvT[n * 256 + k] = (_Float16)Wv[k * 256 + n];
    } else {
        int i = (bid - (C_IN + 257)) * 256 + t;
        int base = i * 4;
        if (base >= E) return;
        if (base + 4 <= E) {
            int4 d4 = *(const int4*)(dst + base);
            int r0 = atomicAdd(&deg[d4.x], 1);
            int r1 = atomicAdd(&deg[d4.y], 1);
            int r2 = atomicAdd(&deg[d4.z], 1);
            int r3 = atomicAdd(&deg[d4.w], 1);
            *(int4*)(rank + base) = make_int4(r0, r1, r2, r3);
        } else {
            for (int k = base; k < E; ++k) rank[k] = atomicAdd(&deg[dst[k]], 1);
        }
    }
}

// ---------------------------------------------------------------------------
// GEMM v12 (proven): M-tile 64, N-tile 128, LDS-staged A+B, fused
// node_scores on y==0.
// ---------------------------------------------------------------------------
__global__ __launch_bounds__(256) void gemm_xv(const float* __restrict__ x,
    const _Float16* __restrict__ WvT, const float* __restrict__ bv,
    const float* __restrict__ Ws, const float* __restrict__ bs,
    _Float16* __restrict__ xv, float* __restrict__ s, int M)
{
    __shared__ __align__(16) _Float16 As[64][40];
    __shared__ __align__(16) _Float16 Bs[128][40];
    int tid = threadIdx.x;
    int wid = tid >> 6, lane = tid & 63;
    int quad = lane >> 4, r16 = lane & 15;
    int m0 = blockIdx.x * 64, n0 = blockIdx.y * 128;
    bool do_s = (blockIdx.y == 0);

    floatx4 acc[8];
#pragma unroll
    for (int j = 0; j < 8; ++j) acc[j] = (floatx4){0.f, 0.f, 0.f, 0.f};

    int arow = tid >> 3, af4 = tid & 7;   // arow 0..31
    int brow = tid >> 2, bg  = tid & 3;   // brow 0..63

    float sacc[2][8];
#pragma unroll
    for (int p = 0; p < 2; ++p)
#pragma unroll
        for (int j = 0; j < 8; ++j) sacc[p][j] = 0.f;

    for (int k0 = 0; k0 < 256; k0 += 32) {
        float w8[4][8];
        if (do_s) {
#pragma unroll
            for (int q = 0; q < 4; ++q) {
                const float4* wr = (const float4*)(Ws + (size_t)(k0 + af4 * 4 + q) * 8);
                float4 wa = wr[0], wb = wr[1];
                w8[q][0] = wa.x; w8[q][1] = wa.y; w8[q][2] = wa.z; w8[q][3] = wa.w;
                w8[q][4] = wb.x; w8[q][5] = wb.y; w8[q][6] = wb.z; w8[q][7] = wb.w;
            }
        }
#pragma unroll
        for (int p = 0; p < 2; ++p) {
            int rr = arow + p * 32;
            int gm = m0 + rr;
            float4 v = make_float4(0.f, 0.f, 0.f, 0.f);
            if (gm < M) v = *(const float4*)(x + (size_t)gm * 256 + k0 + af4 * 4);
            half4v tmp;
            tmp[0] = (_Float16)v.x; tmp[1] = (_Float16)v.y;
            tmp[2] = (_Float16)v.z; tmp[3] = (_Float16)v.w;
            *(half4v*)&As[rr][af4 * 4] = tmp;
            if (do_s) {
                float xq[4] = {v.x, v.y, v.z, v.w};
#pragma unroll
                for (int q = 0; q < 4; ++q)
#pragma unroll
                    for (int j = 0; j < 8; ++j)
                        sacc[p][j] += xq[q] * w8[q][j];
            }
        }
#pragma unroll
        for (int p = 0; p < 2; ++p) {
            int nr = brow + p * 64;
            *(float4*)&Bs[nr][bg * 8] = *(const float4*)(WvT + (size_t)(n0 + nr) * 256 + k0 + bg * 8);
        }
        __syncthreads();
        half8 a = *(const half8*)&As[wid * 16 + r16][quad * 8];
        half8 b[8];
#pragma unroll
        for (int cg = 0; cg < 8; ++cg)
            b[cg] = *(const half8*)&Bs[cg * 16 + r16][quad * 8];
#pragma unroll
        for (int cg = 0; cg < 8; ++cg)
            acc[cg] = __builtin_amdgcn_mfma_f32_16x16x32_f16(a, b[cg], acc[cg], 0, 0, 0);
        __syncthreads();
    }

    if (do_s) {
        float b0[8];
#pragma unroll
        for (int j = 0; j < 8; ++j) b0[j] = bs[j];
#pragma unroll
        for (int p = 0; p < 2; ++p) {
#pragma unroll
            for (int o = 1; o <= 4; o <<= 1)
#pragma unroll
                for (int j = 0; j < 8; ++j)
                    sacc[p][j] += __shfl_xor(sacc[p][j], o, 64);
            int gm = m0 + arow + p * 32;
            if (af4 == 0 && gm < M) {
                *(float4*)(s + (size_t)gm * 8)     = make_float4(sacc[p][0] + b0[0], sacc[p][1] + b0[1], sacc[p][2] + b0[2], sacc[p][3] + b0[3]);
                *(float4*)(s + (size_t)gm * 8 + 4) = make_float4(sacc[p][4] + b0[4], sacc[p][5] + b0[5], sacc[p][6] + b0[6], sacc[p][7] + b0[7]);
            }
        }
    }

#pragma unroll
    for (int cg = 0; cg < 8; ++cg) {
        int gcol = n0 + cg * 16 + r16;
        float bias = bv[gcol];
        int rbase = m0 + wid * 16 + quad * 4;
#pragma unroll
        for (int rr = 0; rr < 4; ++rr) {
            int grow = rbase + rr;
            if (grow < M)
                xv[(size_t)grow * 256 + gcol] = (_Float16)(acc[cg][rr] + bias);
        }
    }
}

// ---------------------------------------------------------------------------
// MID (cooperative, ONE dispatch): scan_part -> scan_final -> scatter -> agg
// with grid.sync() between phases. Phase bodies are verbatim copies of the
// v12 kernels (bit-identical outputs). Grid 1024x256, 4 blocks/CU resident.
// ---------------------------------------------------------------------------
__global__ __launch_bounds__(256, 4) void mid_kernel(
    const int* __restrict__ deg, int* __restrict__ partials, int* __restrict__ offs,
    const int* __restrict__ src, const int* __restrict__ dst,
    const int* __restrict__ rank, int* __restrict__ csr_src,
    const float* __restrict__ s, float* __restrict__ aggl, float* __restrict__ aggr,
    int N, int E, int chunk)
{
    cg::grid_group grid = cg::this_grid();
    int b = blockIdx.x, t = threadIdx.x;
    __shared__ int sd[256];
    __shared__ int sp[256];

    // ---- Phase 1: per-chunk sums (blocks 0..255) ----
    if (b < 256) {
        int idx = b * chunk + t;
        int v = (t < chunk && idx < N) ? deg[idx] : 0;
        sd[t] = v; __syncthreads();
        for (int off = 128; off >= 1; off >>= 1) {
            if (t < off) sd[t] += sd[t + off];
            __syncthreads();
        }
        if (t == 0) partials[b] = sd[0];
    }
    grid.sync();

    // ---- Phase 2: offs (blocks 0..255; local scan of partials) ----
    if (b < 256) {
        int pv = partials[t];
        sp[t] = pv; __syncthreads();
        for (int off = 1; off < 256; off <<= 1) {
            int x = (t >= off) ? sp[t - off] : 0;
            __syncthreads();
            sp[t] += x;
            __syncthreads();
        }
        int base = sp[b] - partials[b];   // exclusive prefix at b
        __syncthreads();

        int idx = b * chunk + t;
        int v = (t < chunk && idx < N) ? deg[idx] : 0;
        sd[t] = v; __syncthreads();
        for (int off = 1; off < 256; off <<= 1) {
            int x = (t >= off) ? sd[t - off] : 0;
            __syncthreads();
            sd[t] += x;
            __syncthreads();
        }
        int incl = sd[t], excl = incl - v;
        if (t < chunk && idx < N) offs[idx] = base + excl;
        if (idx == N - 1) offs[N] = base + incl;  // == E
    }
    grid.sync();

    // ---- Phase 3: scatter (zero atomics; grid-stride, 4 edges/thread) ----
    int nthreads = gridDim.x * 256;
    for (int i = b * 256 + t; i * 4 < E; i += nthreads) {
        int base4 = i * 4;
        if (base4 + 4 <= E) {
            int4 d  = *(const int4*)(dst + base4);
            int4 sv = *(const int4*)(src + base4);
            int4 r  = *(const int4*)(rank + base4);
            csr_src[offs[d.x] + r.x] = sv.x;
            csr_src[offs[d.y] + r.y] = sv.y;
            csr_src[offs[d.z] + r.z] = sv.z;
            csr_src[offs[d.w] + r.w] = sv.w;
        } else {
            for (int k = base4; k < E; ++k)
                csr_src[offs[dst[k]] + rank[k]] = src[k];
        }
    }
    grid.sync();

    // ---- Phase 4: agg (grid-stride over N*8; 8 threads/node) ----
    for (int gid = b * 256 + t; gid < N * 8; gid += nthreads) {
        int n = gid >> 3, c = gid & 7;
        int off = offs[n], dg = deg[n];
        float acc = s[(size_t)n * 8 + c];
        int i = 0;
        for (; i + 4 <= dg; i += 4) {
            int p0 = csr_src[off + i];
            int p1 = csr_src[off + i + 1];
            int p2 = csr_src[off + i + 2];
            int p3 = csr_src[off + i + 3];
            float v0 = s[(size_t)p0 * 8 + c];
            float v1 = s[(size_t)p1 * 8 + c];
            float v2 = s[(size_t)p2 * 8 + c];
            float v3 = s[(size_t)p3 * 8 + c];
            acc += (v0 + v1) + (v2 + v3);
        }
        for (; i < dg; ++i) acc += s[(size_t)csr_src[off + i] * 8 + c];
        acc *= 1.0f / (1.0f + (float)dg);
        if (c < 4) aggl[(size_t)n * 4 + c]     = acc;
        else       aggr[(size_t)n * 4 + c - 4] = acc;
    }
}

// ---------------------------------------------------------------------------
// Fused softmax + value aggregation — v5 (unchanged).
// ---------------------------------------------------------------------------
template<int SZ>
__device__ __forceinline__ void gather_sub(int cs, float w, int base, int grp, int lof,
    const _Float16* __restrict__ xv,
    float& o0, float& o1, float& o2, float& o3)
{
    half4v hv[SZ];
#pragma unroll
    for (int j = 0; j < SZ; ++j) {
        int sidx = __builtin_amdgcn_readlane(cs, base + j);   // SGPR row index
        hv[j] = *(const half4v*)(xv + (((unsigned)sidx << 8) + lof));
    }
#pragma unroll
    for (int j = 0; j < SZ; ++j) {
        float wv = __shfl(w, grp + base + j, 64);
        o0 += wv * (float)hv[j][0];
        o1 += wv * (float)hv[j][1];
        o2 += wv * (float)hv[j][2];
        o3 += wv * (float)hv[j][3];
    }
}

__device__ __forceinline__ void do_chunk(int cs, float w, int cnt, int grp, int lof,
    const _Float16* __restrict__ xv,
    float& o0, float& o1, float& o2, float& o3)
{
    if (cnt == 16) { gather_sub<16>(cs, w, 0, grp, lof, xv, o0, o1, o2, o3); return; }
    int b = 0;
    if (cnt & 8) { gather_sub<8>(cs, w, b, grp, lof, xv, o0, o1, o2, o3); b += 8; }
    if (cnt & 4) { gather_sub<4>(cs, w, b, grp, lof, xv, o0, o1, o2, o3); b += 4; }
    if (cnt & 2) { gather_sub<2>(cs, w, b, grp, lof, xv, o0, o1, o2, o3); b += 2; }
    if (cnt & 1) { gather_sub<1>(cs, w, b, grp, lof, xv, o0, o1, o2, o3); }
}

__global__ __launch_bounds__(256) void attn_out(const float* __restrict__ aggl,
    const float* __restrict__ aggr, const int* __restrict__ csr_src,
    const int* __restrict__ offs, const int* __restrict__ deg,
    const _Float16* __restrict__ xv, float* __restrict__ out, int N)
{
    int wid = threadIdx.x >> 6, lane = threadIdx.x & 63;
    int n = blockIdx.x * 4 + wid;
    if (n >= N) return;
    int myhead = lane >> 4, myedge = lane & 15, grp = lane & 48;
    int lof = lane << 2;
    int off = offs[n], dg = deg[n];
    const int* cb = csr_src + off;
    float ar = aggr[(unsigned)(n * 4 + myhead)];

    float o0 = 0.f, o1 = 0.f, o2 = 0.f, o3 = 0.f;

    int cs0 = 0, cs1 = 0, cs2 = 0, cs3 = 0;
    int e1 = myedge + 16, e2 = myedge + 32, e3 = myedge + 48;
    if (myedge < dg) cs0 = cb[myedge];
    if (e1 < dg)     cs1 = cb[e1];
    if (e2 < dg)     cs2 = cb[e2];
    if (e3 < dg)     cs3 = cb[e3];
    float a0 = 0.f, a1 = 0.f, a2 = 0.f, a3 = 0.f;
    if (myedge < dg) a0 = aggl[(unsigned)((cs0 << 2) + myhead)];
    if (e1 < dg)     a1 = aggl[(unsigned)((cs1 << 2) + myhead)];
    if (e2 < dg)     a2 = aggl[(unsigned)((cs2 << 2) + myhead)];
    if (e3 < dg)     a3 = aggl[(unsigned)((cs3 << 2) + myhead)];
    float w0 = 0.f, w1 = 0.f, w2 = 0.f, w3 = 0.f;
    if (myedge < dg) { float e = a0 + ar; e = (e > 0.f) ? e : NEG_SLOPE * e; w0 = __expf(e); }
    if (e1 < dg)     { float e = a1 + ar; e = (e > 0.f) ? e : NEG_SLOPE * e; w1 = __expf(e); }
    if (e2 < dg)     { float e = a2 + ar; e = (e > 0.f) ? e : NEG_SLOPE * e; w2 = __expf(e); }
    if (e3 < dg)     { float e = a3 + ar; e = (e > 0.f) ? e : NEG_SLOPE * e; w3 = __expf(e); }
    float denom = w0; denom += w1; denom += w2; denom += w3;

    int c0 = dg < 16 ? dg : 16;
    do_chunk(cs0, w0, c0, grp, lof, xv, o0, o1, o2, o3);
    if (dg > 16) {
        int c1 = dg - 16 < 16 ? dg - 16 : 16;
        do_chunk(cs1, w1, c1, grp, lof, xv, o0, o1, o2, o3);
    }
    if (dg > 32) {
        int c2 = dg - 32 < 16 ? dg - 32 : 16;
        do_chunk(cs2, w2, c2, grp, lof, xv, o0, o1, o2, o3);
    }
    if (dg > 48) {
        int c3 = dg - 48 < 16 ? dg - 48 : 16;
        do_chunk(cs3, w3, c3, grp, lof, xv, o0, o1, o2, o3);
    }
    for (int b = 64; b < dg; b += 16) {
        int cs = 0; float w = 0.f;
        if (b + myedge < dg) {
            cs = cb[b + myedge];
            float e = aggl[(unsigned)((cs << 2) + myhead)] + ar;
            e = (e > 0.f) ? e : NEG_SLOPE * e;
            w = __expf(e);
        }
        denom += w;
        int cnt = dg - b < 16 ? dg - b : 16;
        do_chunk(cs, w, cnt, grp, lof, xv, o0, o1, o2, o3);
    }

#pragma unroll
    for (int o = 1; o <= 8; o <<= 1) denom += __shfl_xor(denom, o, 64);
    float inv = 1.0f / fmaxf(denom, 1e-16f);
    floatx4 res = {o0 * inv, o1 * inv, o2 * inv, o3 * inv};
    __builtin_nontemporal_store(res, (floatx4*)(out + (size_t)n * 256 + lof));
}

// ---------------------------------------------------------------------------
extern "C" void kernel_launch(void* const* d_in, const int* in_sizes, int n_in,
                              void* d_out, int out_size, void* d_ws, size_t ws_size,
                              hipStream_t stream)
{
    const float* x    = (const float*)d_in[0];
    const int*   src  = (const int*)d_in[1];
    const int*   dst  = (const int*)d_in[2];
    const float* Wl   = (const float*)d_in[3];
    const float* bl   = (const float*)d_in[4];
    const float* Wr   = (const float*)d_in[5];
    const float* br   = (const float*)d_in[6];
    const float* Wv   = (const float*)d_in[7];
    const float* bv   = (const float*)d_in[8];
    const float* attl = (const float*)d_in[9];
    const float* attr = (const float*)d_in[10];
    float* out = (float*)d_out;

    int N = in_sizes[0] / C_IN;
    int E = in_sizes[1];

    char* p = (char*)d_ws;
    auto alloc = [&](size_t bytes) -> void* {
        uintptr_t q = (uintptr_t)p;
        q = (q + 255) & ~(uintptr_t)255;
        p = (char*)(q + bytes);
        return (void*)q;
    };
    float* Ws     = (float*)alloc((size_t)C_IN * 8 * sizeof(float));
    float* bs     = (float*)alloc(8 * sizeof(float));
    float* s      = (float*)alloc((size_t)N * 8 * sizeof(float));
    float* aggl   = (float*)alloc((size_t)N * 4 * sizeof(float));
    float* aggr   = (float*)alloc((size_t)N * 4 * sizeof(float));
    int* deg      = (int*)alloc((size_t)N * sizeof(int));
    int* offs     = (int*)alloc((size_t)(N + 1) * sizeof(int));
    int* partials = (int*)alloc(256 * sizeof(int));
    int* csr_src  = (int*)alloc((size_t)E * sizeof(int));
    _Float16* WvT = (_Float16*)alloc((size_t)C_IN * C_OUT * sizeof(_Float16));
    _Float16* xv  = (_Float16*)alloc((size_t)N * C_OUT * sizeof(_Float16));

    // rank[i] lives in d_out: only attn_out writes out, AFTER mid_kernel's
    // scatter phase consumed rank. E*4 = 3.2 MB << out_size = 51.2 MB.
    int* rank = (int*)d_out;

    hipMemsetAsync(deg, 0, (size_t)N * sizeof(int), stream);

    int deg_blocks = ((E + 3) / 4 + 255) / 256;
    prep_kernel<<<C_IN + 257 + deg_blocks, 256, 0, stream>>>(
        Wl, Wr, bl, br, attl, attr, Wv, dst, Ws, bs, WvT, deg, rank, E);
    gemm_xv<<<dim3((N + 63) / 64, C_OUT / 128), 256, 0, stream>>>(x, WvT, bv, Ws, bs, xv, s, N);

    int chunk = (N + 255) / 256;
    void* margs[] = { (void*)&deg, (void*)&partials, (void*)&offs,
                      (void*)&src, (void*)&dst, (void*)&rank, (void*)&csr_src,
                      (void*)&s, (void*)&aggl, (void*)&aggr,
                      (void*)&N, (void*)&E, (void*)&chunk };
    hipLaunchCooperativeKernel((void*)mid_kernel, dim3(1024), dim3(256),
                               margs, 0, stream);

    attn_out<<<(N + 3) / 4, 256, 0, stream>>>(aggl, aggr, csr_src, offs, deg, xv, out, N);
}

// Round 14
// 313.215 us; speedup vs baseline: 2.0937x; 2.0937x over previous
//
#include <hip/hip_runtime.h>

#define C_IN 256
#define C_OUT 256
#define NH 4
#define HD 64
#define NEG_SLOPE 0.2f

typedef _Float16 half8 __attribute__((ext_vector_type(8)));
typedef _Float16 half4v __attribute__((ext_vector_type(4)));
typedef float floatx4 __attribute__((ext_vector_type(4)));

// ---------------------------------------------------------------------------
// PREP (merged): blocks [0,256] = make_eff_w; [257,512] = transpose_w;
// [513,...] = deg + RANK (atomicAdd return = within-segment rank).
// ---------------------------------------------------------------------------
__global__ void prep_kernel(const float* __restrict__ Wl, const float* __restrict__ Wr,
                            const float* __restrict__ bl, const float* __restrict__ br,
                            const float* __restrict__ attl, const float* __restrict__ attr,
                            const float* __restrict__ Wv, const int* __restrict__ dst,
                            float* __restrict__ Ws, float* __restrict__ bs,
                            _Float16* __restrict__ WvT, int* __restrict__ deg,
                            int* __restrict__ rank, int E)
{
    int bid = blockIdx.x;
    int t = threadIdx.x;
    if (bid <= C_IN) {
        int c = bid;
        int h = t >> 6, d = t & 63;
        float al = attl[t], ar = attr[t];
        float vl, vr;
        if (c < C_IN) { vl = Wl[c * C_OUT + t] * al; vr = Wr[c * C_OUT + t] * ar; }
        else          { vl = bl[t] * al;             vr = br[t] * ar; }
#pragma unroll
        for (int off = 32; off >= 1; off >>= 1) {
            vl += __shfl_xor(vl, off, 64);
            vr += __shfl_xor(vr, off, 64);
        }
        if (d == 0) {
            if (c < C_IN) { Ws[c * 8 + h] = vl; Ws[c * 8 + 4 + h] = vr; }
            else          { bs[h] = vl;         bs[4 + h] = vr; }
        }
    } else if (bid <= C_IN + 256) {
        int idx = (bid - (C_IN + 1)) * 256 + t;
        int n = idx >> 8, k = idx & 255;
        WvT[n * 256 + k] = (_Float16)Wv[k * 256 + n];
    } else {
        int i = (bid - (C_IN + 257)) * 256 + t;
        int base = i * 4;
        if (base >= E) return;
        if (base + 4 <= E) {
            int4 d4 = *(const int4*)(dst + base);
            int r0 = atomicAdd(&deg[d4.x], 1);
            int r1 = atomicAdd(&deg[d4.y], 1);
            int r2 = atomicAdd(&deg[d4.z], 1);
            int r3 = atomicAdd(&deg[d4.w], 1);
            *(int4*)(rank + base) = make_int4(r0, r1, r2, r3);
        } else {
            for (int k = base; k < E; ++k) rank[k] = atomicAdd(&deg[dst[k]], 1);
        }
    }
}

// ---------------------------------------------------------------------------
// GEMM v14: v12 structure with M-tile 64 -> 32 (traffic-neutral occupancy
// double, same lever as v11->v12). Grid 3126 blocks (12.2/CU), LDS 12.8 KB.
// Waves tile 2x2 over (16-row halves, 64-col halves). Per-row k-order,
// MFMA fragment order, and af4-lane s-reduction identical to v12 ->
// bit-identical outputs.
// ---------------------------------------------------------------------------
__global__ __launch_bounds__(256) void gemm_xv(const float* __restrict__ x,
    const _Float16* __restrict__ WvT, const float* __restrict__ bv,
    const float* __restrict__ Ws, const float* __restrict__ bs,
    _Float16* __restrict__ xv, float* __restrict__ s, int M)
{
    __shared__ __align__(16) _Float16 As[32][40];
    __shared__ __align__(16) _Float16 Bs[128][40];
    int tid = threadIdx.x;
    int wid = tid >> 6, lane = tid & 63;
    int quad = lane >> 4, r16 = lane & 15;
    int m0 = blockIdx.x * 32, n0 = blockIdx.y * 128;
    bool do_s = (blockIdx.y == 0);

    int wrow = (wid & 1) * 16;        // wave's 16-row half
    int wcol = (wid >> 1) * 64;       // wave's 64-col half

    floatx4 acc[4];
#pragma unroll
    for (int j = 0; j < 4; ++j) acc[j] = (floatx4){0.f, 0.f, 0.f, 0.f};

    int arow = tid >> 3, af4 = tid & 7;   // arow 0..31
    int brow = tid >> 2, bg  = tid & 3;   // brow 0..63

    float sacc[8];
#pragma unroll
    for (int j = 0; j < 8; ++j) sacc[j] = 0.f;

    for (int k0 = 0; k0 < 256; k0 += 32) {
        float w8[4][8];
        if (do_s) {
#pragma unroll
            for (int q = 0; q < 4; ++q) {
                const float4* wr = (const float4*)(Ws + (size_t)(k0 + af4 * 4 + q) * 8);
                float4 wa = wr[0], wb = wr[1];
                w8[q][0] = wa.x; w8[q][1] = wa.y; w8[q][2] = wa.z; w8[q][3] = wa.w;
                w8[q][4] = wb.x; w8[q][5] = wb.y; w8[q][6] = wb.z; w8[q][7] = wb.w;
            }
        }
        {
            int gm = m0 + arow;
            float4 v = make_float4(0.f, 0.f, 0.f, 0.f);
            if (gm < M) v = *(const float4*)(x + (size_t)gm * 256 + k0 + af4 * 4);
            half4v tmp;
            tmp[0] = (_Float16)v.x; tmp[1] = (_Float16)v.y;
            tmp[2] = (_Float16)v.z; tmp[3] = (_Float16)v.w;
            *(half4v*)&As[arow][af4 * 4] = tmp;
            if (do_s) {
                float xq[4] = {v.x, v.y, v.z, v.w};
#pragma unroll
                for (int q = 0; q < 4; ++q)
#pragma unroll
                    for (int j = 0; j < 8; ++j)
                        sacc[j] += xq[q] * w8[q][j];
            }
        }
#pragma unroll
        for (int p = 0; p < 2; ++p) {
            int nr = brow + p * 64;
            *(float4*)&Bs[nr][bg * 8] = *(const float4*)(WvT + (size_t)(n0 + nr) * 256 + k0 + bg * 8);
        }
        __syncthreads();
        half8 a = *(const half8*)&As[wrow + r16][quad * 8];
        half8 b[4];
#pragma unroll
        for (int cg = 0; cg < 4; ++cg)
            b[cg] = *(const half8*)&Bs[wcol + cg * 16 + r16][quad * 8];
#pragma unroll
        for (int cg = 0; cg < 4; ++cg)
            acc[cg] = __builtin_amdgcn_mfma_f32_16x16x32_f16(a, b[cg], acc[cg], 0, 0, 0);
        __syncthreads();
    }

    if (do_s) {
        float b0[8];
#pragma unroll
        for (int j = 0; j < 8; ++j) b0[j] = bs[j];
#pragma unroll
        for (int o = 1; o <= 4; o <<= 1)
#pragma unroll
            for (int j = 0; j < 8; ++j)
                sacc[j] += __shfl_xor(sacc[j], o, 64);
        int gm = m0 + arow;
        if (af4 == 0 && gm < M) {
            *(float4*)(s + (size_t)gm * 8)     = make_float4(sacc[0] + b0[0], sacc[1] + b0[1], sacc[2] + b0[2], sacc[3] + b0[3]);
            *(float4*)(s + (size_t)gm * 8 + 4) = make_float4(sacc[4] + b0[4], sacc[5] + b0[5], sacc[6] + b0[6], sacc[7] + b0[7]);
        }
    }

#pragma unroll
    for (int cg = 0; cg < 4; ++cg) {
        int gcol = n0 + wcol + cg * 16 + r16;
        float bias = bv[gcol];
        int rbase = m0 + wrow + quad * 4;
#pragma unroll
        for (int rr = 0; rr < 4; ++rr) {
            int grow = rbase + rr;
            if (grow < M)
                xv[(size_t)grow * 256 + gcol] = (_Float16)(acc[cg][rr] + bias);
        }
    }
}

// ---------------------------------------------------------------------------
// CSR scans (v10-proven).
// ---------------------------------------------------------------------------
__global__ void scan_part(const int* __restrict__ deg, int* __restrict__ partials,
                          int N, int chunk)
{
    __shared__ int sd[256];
    int b = blockIdx.x, t = threadIdx.x;
    int idx = b * chunk + t;
    int v = (t < chunk && idx < N) ? deg[idx] : 0;
    sd[t] = v; __syncthreads();
    for (int off = 128; off >= 1; off >>= 1) {
        if (t < off) sd[t] += sd[t + off];
        __syncthreads();
    }
    if (t == 0) partials[b] = sd[0];
}

__global__ void scan_final(const int* __restrict__ deg, const int* __restrict__ partials,
                           int* __restrict__ offs, int N, int chunk)
{
    __shared__ int sp[256];
    __shared__ int sd[256];
    int b = blockIdx.x, t = threadIdx.x;
    int pv = partials[t];
    sp[t] = pv; __syncthreads();
    for (int off = 1; off < 256; off <<= 1) {
        int x = (t >= off) ? sp[t - off] : 0;
        __syncthreads();
        sp[t] += x;
        __syncthreads();
    }
    int base = sp[b] - partials[b];   // exclusive prefix at b
    __syncthreads();

    int idx = b * chunk + t;
    int v = (t < chunk && idx < N) ? deg[idx] : 0;
    sd[t] = v; __syncthreads();
    for (int off = 1; off < 256; off <<= 1) {
        int x = (t >= off) ? sd[t - off] : 0;
        __syncthreads();
        sd[t] += x;
        __syncthreads();
    }
    int incl = sd[t], excl = incl - v;
    if (t < chunk && idx < N) offs[idx] = base + excl;
    if (idx == N - 1) offs[N] = base + incl;  // == E
}

// ---------------------------------------------------------------------------
// Scatter (v11-proven, zero atomics).
// ---------------------------------------------------------------------------
__global__ void scatter_kernel(const int* __restrict__ src, const int* __restrict__ dst,
                               const int* __restrict__ offs, const int* __restrict__ rank,
                               int* __restrict__ csr_src, int E)
{
    int i = blockIdx.x * 256 + threadIdx.x;
    int base = i * 4;
    if (base >= E) return;
    if (base + 4 <= E) {
        int4 d  = *(const int4*)(dst + base);
        int4 sv = *(const int4*)(src + base);
        int4 r  = *(const int4*)(rank + base);
        csr_src[offs[d.x] + r.x] = sv.x;
        csr_src[offs[d.y] + r.y] = sv.y;
        csr_src[offs[d.z] + r.z] = sv.z;
        csr_src[offs[d.w] + r.w] = sv.w;
    } else {
        for (int k = base; k < E; ++k)
            csr_src[offs[dst[k]] + rank[k]] = src[k];
    }
}

// ---------------------------------------------------------------------------
// agg = (hlr + segsum(hlr[src] by dst)) / (1+deg). EIGHT threads per node.
// ---------------------------------------------------------------------------
__global__ void agg_kernel(const float* __restrict__ s, const int* __restrict__ csr_src,
                           const int* __restrict__ offs, const int* __restrict__ deg,
                           float* __restrict__ aggl, float* __restrict__ aggr, int N)
{
    int gid = blockIdx.x * 256 + threadIdx.x;
    int n = gid >> 3, c = gid & 7;
    if (n >= N) return;
    int off = offs[n], dg = deg[n];
    float acc = s[(size_t)n * 8 + c];
    int i = 0;
    for (; i + 4 <= dg; i += 4) {
        int p0 = csr_src[off + i];
        int p1 = csr_src[off + i + 1];
        int p2 = csr_src[off + i + 2];
        int p3 = csr_src[off + i + 3];
        float v0 = s[(size_t)p0 * 8 + c];
        float v1 = s[(size_t)p1 * 8 + c];
        float v2 = s[(size_t)p2 * 8 + c];
        float v3 = s[(size_t)p3 * 8 + c];
        acc += (v0 + v1) + (v2 + v3);
    }
    for (; i < dg; ++i) acc += s[(size_t)csr_src[off + i] * 8 + c];
    acc *= 1.0f / (1.0f + (float)dg);
    if (c < 4) aggl[(size_t)n * 4 + c]     = acc;
    else       aggr[(size_t)n * 4 + c - 4] = acc;
}

// ---------------------------------------------------------------------------
// Fused softmax + value aggregation — v5 (unchanged).
// ---------------------------------------------------------------------------
template<int SZ>
__device__ __forceinline__ void gather_sub(int cs, float w, int base, int grp, int lof,
    const _Float16* __restrict__ xv,
    float& o0, float& o1, float& o2, float& o3)
{
    half4v hv[SZ];
#pragma unroll
    for (int j = 0; j < SZ; ++j) {
        int sidx = __builtin_amdgcn_readlane(cs, base + j);   // SGPR row index
        hv[j] = *(const half4v*)(xv + (((unsigned)sidx << 8) + lof));
    }
#pragma unroll
    for (int j = 0; j < SZ; ++j) {
        float wv = __shfl(w, grp + base + j, 64);
        o0 += wv * (float)hv[j][0];
        o1 += wv * (float)hv[j][1];
        o2 += wv * (float)hv[j][2];
        o3 += wv * (float)hv[j][3];
    }
}

__device__ __forceinline__ void do_chunk(int cs, float w, int cnt, int grp, int lof,
    const _Float16* __restrict__ xv,
    float& o0, float& o1, float& o2, float& o3)
{
    if (cnt == 16) { gather_sub<16>(cs, w, 0, grp, lof, xv, o0, o1, o2, o3); return; }
    int b = 0;
    if (cnt & 8) { gather_sub<8>(cs, w, b, grp, lof, xv, o0, o1, o2, o3); b += 8; }
    if (cnt & 4) { gather_sub<4>(cs, w, b, grp, lof, xv, o0, o1, o2, o3); b += 4; }
    if (cnt & 2) { gather_sub<2>(cs, w, b, grp, lof, xv, o0, o1, o2, o3); b += 2; }
    if (cnt & 1) { gather_sub<1>(cs, w, b, grp, lof, xv, o0, o1, o2, o3); }
}

__global__ __launch_bounds__(256) void attn_out(const float* __restrict__ aggl,
    const float* __restrict__ aggr, const int* __restrict__ csr_src,
    const int* __restrict__ offs, const int* __restrict__ deg,
    const _Float16* __restrict__ xv, float* __restrict__ out, int N)
{
    int wid = threadIdx.x >> 6, lane = threadIdx.x & 63;
    int n = blockIdx.x * 4 + wid;
    if (n >= N) return;
    int myhead = lane >> 4, myedge = lane & 15, grp = lane & 48;
    int lof = lane << 2;
    int off = offs[n], dg = deg[n];
    const int* cb = csr_src + off;
    float ar = aggr[(unsigned)(n * 4 + myhead)];

    float o0 = 0.f, o1 = 0.f, o2 = 0.f, o3 = 0.f;

    int cs0 = 0, cs1 = 0, cs2 = 0, cs3 = 0;
    int e1 = myedge + 16, e2 = myedge + 32, e3 = myedge + 48;
    if (myedge < dg) cs0 = cb[myedge];
    if (e1 < dg)     cs1 = cb[e1];
    if (e2 < dg)     cs2 = cb[e2];
    if (e3 < dg)     cs3 = cb[e3];
    float a0 = 0.f, a1 = 0.f, a2 = 0.f, a3 = 0.f;
    if (myedge < dg) a0 = aggl[(unsigned)((cs0 << 2) + myhead)];
    if (e1 < dg)     a1 = aggl[(unsigned)((cs1 << 2) + myhead)];
    if (e2 < dg)     a2 = aggl[(unsigned)((cs2 << 2) + myhead)];
    if (e3 < dg)     a3 = aggl[(unsigned)((cs3 << 2) + myhead)];
    float w0 = 0.f, w1 = 0.f, w2 = 0.f, w3 = 0.f;
    if (myedge < dg) { float e = a0 + ar; e = (e > 0.f) ? e : NEG_SLOPE * e; w0 = __expf(e); }
    if (e1 < dg)     { float e = a1 + ar; e = (e > 0.f) ? e : NEG_SLOPE * e; w1 = __expf(e); }
    if (e2 < dg)     { float e = a2 + ar; e = (e > 0.f) ? e : NEG_SLOPE * e; w2 = __expf(e); }
    if (e3 < dg)     { float e = a3 + ar; e = (e > 0.f) ? e : NEG_SLOPE * e; w3 = __expf(e); }
    float denom = w0; denom += w1; denom += w2; denom += w3;

    int c0 = dg < 16 ? dg : 16;
    do_chunk(cs0, w0, c0, grp, lof, xv, o0, o1, o2, o3);
    if (dg > 16) {
        int c1 = dg - 16 < 16 ? dg - 16 : 16;
        do_chunk(cs1, w1, c1, grp, lof, xv, o0, o1, o2, o3);
    }
    if (dg > 32) {
        int c2 = dg - 32 < 16 ? dg - 32 : 16;
        do_chunk(cs2, w2, c2, grp, lof, xv, o0, o1, o2, o3);
    }
    if (dg > 48) {
        int c3 = dg - 48 < 16 ? dg - 48 : 16;
        do_chunk(cs3, w3, c3, grp, lof, xv, o0, o1, o2, o3);
    }
    for (int b = 64; b < dg; b += 16) {
        int cs = 0; float w = 0.f;
        if (b + myedge < dg) {
            cs = cb[b + myedge];
            float e = aggl[(unsigned)((cs << 2) + myhead)] + ar;
            e = (e > 0.f) ? e : NEG_SLOPE * e;
            w = __expf(e);
        }
        denom += w;
        int cnt = dg - b < 16 ? dg - b : 16;
        do_chunk(cs, w, cnt, grp, lof, xv, o0, o1, o2, o3);
    }

#pragma unroll
    for (int o = 1; o <= 8; o <<= 1) denom += __shfl_xor(denom, o, 64);
    float inv = 1.0f / fmaxf(denom, 1e-16f);
    floatx4 res = {o0 * inv, o1 * inv, o2 * inv, o3 * inv};
    __builtin_nontemporal_store(res, (floatx4*)(out + (size_t)n * 256 + lof));
}

// ---------------------------------------------------------------------------
extern "C" void kernel_launch(void* const* d_in, const int* in_sizes, int n_in,
                              void* d_out, int out_size, void* d_ws, size_t ws_size,
                              hipStream_t stream)
{
    const float* x    = (const float*)d_in[0];
    const int*   src  = (const int*)d_in[1];
    const int*   dst  = (const int*)d_in[2];
    const float* Wl   = (const float*)d_in[3];
    const float* bl   = (const float*)d_in[4];
    const float* Wr   = (const float*)d_in[5];
    const float* br   = (const float*)d_in[6];
    const float* Wv   = (const float*)d_in[7];
    const float* bv   = (const float*)d_in[8];
    const float* attl = (const float*)d_in[9];
    const float* attr = (const float*)d_in[10];
    float* out = (float*)d_out;

    int N = in_sizes[0] / C_IN;
    int E = in_sizes[1];

    char* p = (char*)d_ws;
    auto alloc = [&](size_t bytes) -> void* {
        uintptr_t q = (uintptr_t)p;
        q = (q + 255) & ~(uintptr_t)255;
        p = (char*)(q + bytes);
        return (void*)q;
    };
    float* Ws     = (float*)alloc((size_t)C_IN * 8 * sizeof(float));
    float* bs     = (float*)alloc(8 * sizeof(float));
    float* s      = (float*)alloc((size_t)N * 8 * sizeof(float));
    float* aggl   = (float*)alloc((size_t)N * 4 * sizeof(float));
    float* aggr   = (float*)alloc((size_t)N * 4 * sizeof(float));
    int* deg      = (int*)alloc((size_t)N * sizeof(int));
    int* offs     = (int*)alloc((size_t)(N + 1) * sizeof(int));
    int* partials = (int*)alloc(256 * sizeof(int));
    int* csr_src  = (int*)alloc((size_t)E * sizeof(int));
    _Float16* WvT = (_Float16*)alloc((size_t)C_IN * C_OUT * sizeof(_Float16));
    _Float16* xv  = (_Float16*)alloc((size_t)N * C_OUT * sizeof(_Float16));

    // rank[i] lives in d_out: only attn_out writes out, AFTER scatter
    // consumed rank. E*4 = 3.2 MB << out_size = 51.2 MB.
    int* rank = (int*)d_out;

    hipMemsetAsync(deg, 0, (size_t)N * sizeof(int), stream);

    int deg_blocks = ((E + 3) / 4 + 255) / 256;
    prep_kernel<<<C_IN + 257 + deg_blocks, 256, 0, stream>>>(
        Wl, Wr, bl, br, attl, attr, Wv, dst, Ws, bs, WvT, deg, rank, E);
    gemm_xv<<<dim3((N + 31) / 32, C_OUT / 128), 256, 0, stream>>>(x, WvT, bv, Ws, bs, xv, s, N);
    int chunk = (N + 255) / 256;
    scan_part<<<256, 256, 0, stream>>>(deg, partials, N, chunk);
    scan_final<<<256, 256, 0, stream>>>(deg, partials, offs, N, chunk);
    scatter_kernel<<<((E + 3) / 4 + 255) / 256, 256, 0, stream>>>(src, dst, offs, rank, csr_src, E);
    agg_kernel<<<(N * 8 + 255) / 256, 256, 0, stream>>>(s, csr_src, offs, deg, aggl, aggr, N);
    attn_out<<<(N + 3) / 4, 256, 0, stream>>>(aggl, aggr, csr_src, offs, deg, xv, out, N);
}